// Round 7
// baseline (228.225 us; speedup 1.0000x reference)
//
#include <hip/hip_runtime.h>
#include <hip/hip_fp16.h>
#include <hip/hip_cooperative_groups.h>
#include <math.h>

namespace cg = cooperative_groups;

#define NEARP 0.01f
#define BLUR 0.3f
#define MAX_ALPHA 0.999f
#define TILE 16
#define QCUT 32.0f   // mahalanobis^2 cutoff: culled alpha <= op*e^-16 ~ 1e-7
#define ABLK 512
#define ATHR 256
#define RSEG 16      // waves per render block; each lane handles 4 pixels

struct PParams {
    const float* viewmats;
    const float* Ks;
    const float* means;
    const float* quats;
    const float* log_scales;
    const float* opac_logits;
    const float* color_logits;
    float4* ubbox;   // C*N   (m2x, m2y, r, 0)
    float4* upay;    // C*N*2 f0=(m2x,m2y,iap,ibp) f1=(icp,op,rg_half2,b)
    float4* sbbox;   // C*N sorted
    float4* spay;    // C*N*2 sorted
    float* tz;       // C*N
    int N, C, phase;
};

__device__ __forceinline__ float sigmoidf_(float x) {
    return 1.0f / (1.0f + expf(-x));
}

// ---------------------------------------------------------------------------
// Phase 1: per-(camera,gaussian) preprocess (conic pre-scaled for exp2)
// ---------------------------------------------------------------------------
__device__ void do_preprocess(const PParams& p, int tid, int tot) {
    for (int idx = tid; idx < p.N * p.C; idx += tot) {
        int c = idx / p.N;
        int n = idx - c * p.N;

        float qw = p.quats[n * 4 + 0], qx = p.quats[n * 4 + 1];
        float qy = p.quats[n * 4 + 2], qz = p.quats[n * 4 + 3];
        float qn = rsqrtf(qw * qw + qx * qx + qy * qy + qz * qz);
        float w = qw * qn, x = qx * qn, y = qy * qn, z = qz * qn;
        float R00 = 1.0f - 2.0f * (y * y + z * z), R01 = 2.0f * (x * y - w * z), R02 = 2.0f * (x * z + w * y);
        float R10 = 2.0f * (x * y + w * z), R11 = 1.0f - 2.0f * (x * x + z * z), R12 = 2.0f * (y * z - w * x);
        float R20 = 2.0f * (x * z - w * y), R21 = 2.0f * (y * z + w * x), R22 = 1.0f - 2.0f * (x * x + y * y);

        float s0 = expf(p.log_scales[n * 3 + 0]);
        float s1 = expf(p.log_scales[n * 3 + 1]);
        float s2 = expf(p.log_scales[n * 3 + 2]);

        float M00 = R00 * s0, M01 = R01 * s1, M02 = R02 * s2;
        float M10 = R10 * s0, M11 = R11 * s1, M12 = R12 * s2;
        float M20 = R20 * s0, M21 = R21 * s1, M22 = R22 * s2;
        float C00 = M00 * M00 + M01 * M01 + M02 * M02;
        float C01 = M00 * M10 + M01 * M11 + M02 * M12;
        float C02 = M00 * M20 + M01 * M21 + M02 * M22;
        float C11 = M10 * M10 + M11 * M11 + M12 * M12;
        float C12 = M10 * M20 + M11 * M21 + M12 * M22;
        float C22 = M20 * M20 + M21 * M21 + M22 * M22;

        const float* vm = p.viewmats + c * 16;
        float V00 = vm[0], V01 = vm[1], V02 = vm[2], T0 = vm[3];
        float V10 = vm[4], V11 = vm[5], V12 = vm[6], T1 = vm[7];
        float V20 = vm[8], V21 = vm[9], V22 = vm[10], T2 = vm[11];
        float mex = p.means[n * 3 + 0], mey = p.means[n * 3 + 1], mez = p.means[n * 3 + 2];
        float tx = V00 * mex + V01 * mey + V02 * mez + T0;
        float ty = V10 * mex + V11 * mey + V12 * mez + T1;
        float tzv = V20 * mex + V21 * mey + V22 * mez + T2;

        float fx = p.Ks[c * 9 + 0], fy = p.Ks[c * 9 + 4], cx = p.Ks[c * 9 + 2], cy = p.Ks[c * 9 + 5];
        float tzs = (tzv > NEARP) ? tzv : NEARP;
        float iz = 1.0f / tzs;
        float m2x = fx * tx * iz + cx;
        float m2y = fy * ty * iz + cy;

        float A00 = V00 * C00 + V01 * C01 + V02 * C02;
        float A01 = V00 * C01 + V01 * C11 + V02 * C12;
        float A02 = V00 * C02 + V01 * C12 + V02 * C22;
        float A10 = V10 * C00 + V11 * C01 + V12 * C02;
        float A11 = V10 * C01 + V11 * C11 + V12 * C12;
        float A12 = V10 * C02 + V11 * C12 + V12 * C22;
        float A20 = V20 * C00 + V21 * C01 + V22 * C02;
        float A21 = V20 * C01 + V21 * C11 + V22 * C12;
        float A22 = V20 * C02 + V21 * C12 + V22 * C22;
        float S00 = A00 * V00 + A01 * V01 + A02 * V02;
        float S01 = A00 * V10 + A01 * V11 + A02 * V12;
        float S02 = A00 * V20 + A01 * V21 + A02 * V22;
        float S11 = A10 * V10 + A11 * V11 + A12 * V12;
        float S12 = A10 * V20 + A11 * V21 + A12 * V22;
        float S22 = A20 * V20 + A21 * V21 + A22 * V22;

        float J00 = fx * iz, J02 = -fx * tx * iz * iz;
        float J11 = fy * iz, J12 = -fy * ty * iz * iz;

        float c2_00 = J00 * J00 * S00 + 2.0f * J00 * J02 * S02 + J02 * J02 * S22;
        float c2_01 = J00 * J11 * S01 + J00 * J12 * S02 + J02 * J11 * S12 + J02 * J12 * S22;
        float c2_11 = J11 * J11 * S11 + 2.0f * J11 * J12 * S12 + J12 * J12 * S22;

        float a = c2_00 + BLUR;
        float cc = c2_11 + BLUR;
        float b = c2_01;
        float det = a * cc - b * b;
        bool valid = (tzv > NEARP) && (det > 1e-12f);

        float ia, ib, ic, op, r;
        if (valid) {
            float inv = 1.0f / det;
            ia = cc * inv;
            ib = -b * inv;
            ic = a * inv;
            op = sigmoidf_(p.opac_logits[n]);
            float lmax = 0.5f * (a + cc) + sqrtf(0.25f * (a - cc) * (a - cc) + b * b);
            r = sqrtf(QCUT * lmax);
        } else {
            ia = 0.0f; ib = 0.0f; ic = 0.0f; op = 0.0f;
            r = -1.0f;   // culled from every tile; exact contribution is 0 anyway
        }
        float cr = sigmoidf_(p.color_logits[n * 3 + 0]);
        float cg_ = sigmoidf_(p.color_logits[n * 3 + 1]);
        float cb = sigmoidf_(p.color_logits[n * 3 + 2]);

        const float KQ = 0.721347520444482f;   // 0.5*log2(e)
        float iap = -KQ * ia;
        float ibp = -2.0f * KQ * ib;
        float icp = -KQ * ic;

        union { __half2 h; float f; } pk;
        pk.h = __floats2half2_rn(cr, cg_);

        int gi = c * p.N + n;
        p.ubbox[gi] = make_float4(m2x, m2y, r, 0.0f);
        p.upay[(size_t)gi * 2 + 0] = make_float4(m2x, m2y, iap, ibp);
        p.upay[(size_t)gi * 2 + 1] = make_float4(icp, op, pk.f, cb);
        p.tz[gi] = tzv;
    }
}

// ---------------------------------------------------------------------------
// Phase 2: wave-per-element stable rank sort; scatter bbox+payload to rank.
// ---------------------------------------------------------------------------
__device__ void do_sort(const PParams& p, int wave, int lane, int totWaves) {
    for (int w = wave; w < p.C * p.N; w += totWaves) {
        int c = w / p.N;
        int i = w - c * p.N;
        const float* tzc = p.tz + (size_t)c * p.N;
        float ti = tzc[i];
        int rank = 0;
        for (int j = lane; j < p.N; j += 64) {
            float tj = tzc[j];
            rank += (int)((tj < ti) || (tj == ti && j < i));   // stable
        }
#pragma unroll
        for (int off = 1; off < 64; off <<= 1)
            rank += __shfl_xor(rank, off, 64);
        int src = c * p.N + i;
        int dst = c * p.N + rank;
        if (lane == 0) p.sbbox[dst] = p.ubbox[src];
        if (lane < 2) p.spay[(size_t)dst * 2 + lane] = p.upay[(size_t)src * 2 + lane];
    }
}

__global__ void __launch_bounds__(ATHR, 2) gs_prep_sort(PParams p) {
    int tid = blockIdx.x * blockDim.x + threadIdx.x;
    int tot = gridDim.x * blockDim.x;
    if (p.phase == 0 || p.phase == 1) do_preprocess(p, tid, tot);
    if (p.phase == 0) { __threadfence(); cg::this_grid().sync(); }
    if (p.phase == 0 || p.phase == 2) do_sort(p, tid >> 6, tid & 63, tot >> 6);
}

// ---------------------------------------------------------------------------
// Render: block = one 16x16 tile. 16 waves; wave w composites rank-segment w
// (ballot-culled per 64-chunk) for all 256 px (4 px/lane). Ordered in-block
// fold of the 16 segment partials in LDS, then direct store to out.
// ---------------------------------------------------------------------------
__global__ void __launch_bounds__(RSEG * 64) gs_render_fused(
        const float4* __restrict__ sbbox,
        const float4* __restrict__ spay,
        float* __restrict__ out,
        int N, int W, int H) {
    __shared__ float4 part[RSEG * 256];
    int c = blockIdx.z;
    float x0 = (float)(blockIdx.x * TILE);
    float y0 = (float)(blockIdx.y * TILE);
    float x1 = x0 + (float)TILE;
    float y1 = y0 + (float)TILE;
    int wv = threadIdx.x >> 6;
    int lane = threadIdx.x & 63;

    int nchunk = (N + 63) >> 6;
    int cpseg = (nchunk + RSEG - 1) / RSEG;
    int v0 = wv * cpseg;
    int v1 = min(nchunk, v0 + cpseg);

    const float4* bb = sbbox + (size_t)c * N;
    const float4* pay = spay + (size_t)c * N * 2;

    float pxv[4], pyv[4], ar[4], ag[4], ab[4], at[4];
#pragma unroll
    for (int q = 0; q < 4; q++) {
        int pq = q * 64 + lane;
        pxv[q] = x0 + (float)(pq & 15) + 0.5f;
        pyv[q] = y0 + (float)(pq >> 4) + 0.5f;
        ar[q] = 0.0f; ag[q] = 0.0f; ab[q] = 0.0f; at[q] = 1.0f;
    }

    for (int v = v0; v < v1; v++) {
        int g = v * 64 + lane;
        bool pred = false;
        if (g < N) {
            float4 b = bb[g];
            pred = (b.z >= 0.0f) &&
                   (b.x - b.z <= x1) && (b.x + b.z >= x0) &&
                   (b.y - b.z <= y1) && (b.y + b.z >= y0);
        }
        unsigned long long m = __ballot(pred);
        for (; m; m &= (m - 1)) {
            int gg = v * 64 + (__ffsll((unsigned long long)m) - 1);   // asc rank
            float4 f0 = pay[(size_t)gg * 2 + 0];
            float4 f1 = pay[(size_t)gg * 2 + 1];
            union { float f; __half2 h; } pk; pk.f = f1.z;
            float crv = __low2float(pk.h);
            float cgv = __high2float(pk.h);
#pragma unroll
            for (int q = 0; q < 4; q++) {
                float dx = pxv[q] - f0.x;
                float dy = pyv[q] - f0.y;
                float quad = dx * (f0.z * dx + f0.w * dy) + f1.x * dy * dy;  // <= 0
                float alpha = fminf(f1.y * exp2f(quad), MAX_ALPHA);
                float wgt = alpha * at[q];
                ar[q] += wgt * crv;
                ag[q] += wgt * cgv;
                ab[q] += wgt * f1.w;
                at[q] *= (1.0f - alpha);
            }
        }
    }
#pragma unroll
    for (int q = 0; q < 4; q++)
        part[wv * 256 + q * 64 + lane] = make_float4(ar[q], ag[q], ab[q], at[q]);
    __syncthreads();

    if (threadIdx.x < 256) {
        int pq = threadIdx.x;
        float R = 0.0f, G = 0.0f, B = 0.0f, T = 1.0f;
#pragma unroll
        for (int s = 0; s < RSEG; s++) {
            float4 a = part[s * 256 + pq];
            R += T * a.x;
            G += T * a.y;
            B += T * a.z;
            T *= a.w;
        }
        int x = blockIdx.x * TILE + (pq & 15);
        int y = blockIdx.y * TILE + (pq >> 4);
        if (x < W && y < H) {
            size_t o = (((size_t)c * H + y) * W + x) * 3;
            out[o + 0] = R;
            out[o + 1] = G;
            out[o + 2] = B;
        }
    }
}

extern "C" void kernel_launch(void* const* d_in, const int* in_sizes, int n_in,
                              void* d_out, int out_size, void* d_ws, size_t ws_size,
                              hipStream_t stream) {
    int N = in_sizes[2] / 3;       // means: (N,3)
    int C = in_sizes[0] / 16;      // viewmats: (C,4,4)
    int pix = out_size / (C * 3);
    int W = (int)(sqrt((double)pix) + 0.5);
    int H = pix / W;
    int tilesx = (W + TILE - 1) / TILE;
    int tilesy = (H + TILE - 1) / TILE;

    PParams prm;
    prm.viewmats = (const float*)d_in[0];
    prm.Ks = (const float*)d_in[1];
    prm.means = (const float*)d_in[2];
    prm.quats = (const float*)d_in[3];
    prm.log_scales = (const float*)d_in[4];
    prm.opac_logits = (const float*)d_in[5];
    prm.color_logits = (const float*)d_in[6];

    float4* ws4 = (float4*)d_ws;
    prm.ubbox = ws4;                                  // C*N
    prm.sbbox = prm.ubbox + (size_t)C * N;            // C*N
    prm.upay  = prm.sbbox + (size_t)C * N;            // C*N*2
    prm.spay  = prm.upay + (size_t)C * N * 2;         // C*N*2
    prm.tz    = (float*)(prm.spay + (size_t)C * N * 2);  // C*N
    prm.N = N; prm.C = C; prm.phase = 0;

    void* args[] = { &prm };
    hipError_t err = hipLaunchCooperativeKernel((void*)gs_prep_sort,
                                                dim3(ABLK), dim3(ATHR), args, 0, stream);
    if (err != hipSuccess) {
        PParams p1 = prm; p1.phase = 1;
        hipLaunchKernelGGL(gs_prep_sort, dim3(ABLK), dim3(ATHR), 0, stream, p1);
        PParams p2 = prm; p2.phase = 2;
        hipLaunchKernelGGL(gs_prep_sort, dim3(ABLK), dim3(ATHR), 0, stream, p2);
    }

    dim3 rgrid(tilesx, tilesy, C);
    gs_render_fused<<<rgrid, RSEG * 64, 0, stream>>>(
        prm.sbbox, prm.spay, (float*)d_out, N, W, H);
}